// Round 8
// baseline (78.667 us; speedup 1.0000x reference)
//
#include <hip/hip_runtime.h>

// R8 = CONTROL: byte-identical resubmission of the verified R3 kernel
// (passed round 3: 44us kernel, absmax 3.9e-3). Rounds 4-7 made four
// independent, individually-audited changes (8-wave block; K-split+ws;
// M-split; K-split+atomics) and ALL failed with absmax ~0.97-1.0 while no
// static audit finds a bug. This round re-anchors: if R3 still passes, the
// failures live in the restructure delta-space (or 8-wave/CU envelope);
// if it now fails, R3's original pass was the outlier (latent race or
// harness nondeterminism) and the whole plan changes. Pure control - no
// functional delta vs round 3.

#define WIDTH 60
#define LCURVES 160
#define NSAMP 30
#define NEG_INVA_LOG2E (-7213.4752f)   // -(1/alpha)*log2(e) = -5000*1.442695

typedef _Float16 half8 __attribute__((ext_vector_type(8)));
typedef float floatx4 __attribute__((ext_vector_type(4)));

__global__ __launch_bounds__(256) void bezier_mfma_kernel(
    const float* __restrict__ x, float* __restrict__ out) {
    // 4 waves x (Gx + Gy) x 64x64 f16 = 65536 B; reused as reduction buffer.
    __shared__ __align__(16) char smem[65536];

    const int tid = threadIdx.x;
    const int lane = tid & 63;
    const int w = tid >> 6;          // wave id 0..3
    const int b = blockIdx.x;
    const int m = lane & 15;         // fragment row/col within 16
    const int q = lane >> 4;         // quad 0..3

    // zero all tiles (4096 float4s)
    float4* sz = (float4*)smem;
#pragma unroll
    for (int i = 0; i < 16; ++i)
        sz[tid + 256 * i] = make_float4(0.f, 0.f, 0.f, 0.f);
    __syncthreads();

    _Float16* gx = (_Float16*)(smem + w * 16384);  // [64 rows][64 cols] swizzled
    _Float16* gy = gx + 4096;

    floatx4 acc[4][4];
#pragma unroll
    for (int ti = 0; ti < 4; ++ti)
#pragma unroll
        for (int tj = 0; tj < 4; ++tj)
            acc[ti][tj] = (floatx4){0.f, 0.f, 0.f, 0.f};

    const float* xb = x + (size_t)b * (LCURVES * 8);
    int prev_i0 = 0, prev_j0 = 0;   // first-iter zeroing hits already-zero cells

    // 75 chunks of 64 splats; wave w takes chunks w, w+4, ... (disjoint K)
    for (int c = w; c < 75; c += 4) {
        int s = c * 64 + lane;            // this lane's splat = its k-column
        int l = s % LCURVES;
        int n = s / LCURVES;

        const float4* cp = (const float4*)(xb + l * 8);
        float4 c0 = cp[0];  // x0 y0 x1 y1
        float4 c1 = cp[1];  // x2 y2 x3 y3

        // warped Bernstein basis (matches reference _bezier_basis)
        float tt = (float)n * (1.0f / NSAMP);
        tt = 2.0f * tt * tt * tt - 3.0f * tt * tt + 2.0f * tt;
        float tb = 1.0f - tt, t2 = tt * tt;
        float w0 = t2 * tt;
        float w1 = 3.0f * (t2 - w0);
        float w2 = 3.0f * tt * tb * tb;
        float w3 = tb * tb * tb;
        float X = w0 * c0.x + w1 * c0.z + w2 * c1.x + w3 * c1.z;
        float Y = w0 * c0.y + w1 * c0.w + w2 * c1.y + w3 * c1.w;

        int i0 = (int)floorf(X * (float)WIDTH);
        int j0 = (int)floorf(Y * (float)WIDTH);
        i0 = min(max(i0, 0), 59);
        j0 = min(max(j0, 0), 59);

        // zero previous chunk's 12 cells (same lane, in-order DS -> safe),
        // then write this chunk's 12 tap weights. No other lane touches
        // column `lane`, so plain stores suffice.
#pragma unroll
        for (int a = 0; a < 6; ++a) {
            int rz = min(prev_i0 + a, 63);
            gx[rz * 64 + (lane ^ ((rz & 7) << 3))] = (_Float16)0;
            int rz2 = min(prev_j0 + a, 63);
            gy[rz2 * 64 + (lane ^ ((rz2 & 7) << 3))] = (_Float16)0;
        }
        float bx = (float)(i0 - 2) * (1.0f / WIDTH) - X;
        float by = (float)(j0 - 2) * (1.0f / WIDTH) - Y;
#pragma unroll
        for (int a = 0; a < 6; ++a) {
            float dx = bx + (float)a * (1.0f / WIDTH);
            float vx = __builtin_amdgcn_exp2f(dx * dx * NEG_INVA_LOG2E);
            int r = min(i0 + a, 63);
            gx[r * 64 + (lane ^ ((r & 7) << 3))] = (_Float16)vx;
            float dy = by + (float)a * (1.0f / WIDTH);
            float vy = __builtin_amdgcn_exp2f(dy * dy * NEG_INVA_LOG2E);
            int r2 = min(j0 + a, 63);
            gy[r2 * 64 + (lane ^ ((r2 & 7) << 3))] = (_Float16)vy;
        }
        prev_i0 = i0;
        prev_j0 = j0;

        // MFMA over this chunk's K=64: A[m][k]=gx(row m)[k], B[k][n]=gy(row n)[k]
        // A-frag: lane(m,q) holds k = kk*32 + q*8 + j ; swizzled col base =
        // 8*((kk*4+q) ^ (row&7)) -> contiguous 16B -> ds_read_b128.
#pragma unroll
        for (int kk = 0; kk < 2; ++kk) {
            half8 af[4], bf[4];
#pragma unroll
            for (int t = 0; t < 4; ++t) {
                int ra = t * 16 + m;
                af[t] = *(const half8*)&gx[ra * 64 + (((kk * 4 + q) ^ (ra & 7)) << 3)];
                bf[t] = *(const half8*)&gy[ra * 64 + (((kk * 4 + q) ^ (ra & 7)) << 3)];
            }
#pragma unroll
            for (int ti = 0; ti < 4; ++ti)
#pragma unroll
                for (int tj = 0; tj < 4; ++tj)
                    acc[ti][tj] = __builtin_amdgcn_mfma_f32_16x16x32_f16(
                        af[ti], bf[tj], acc[ti][tj], 0, 0, 0);
        }
    }

    // Reduce the 4 K-partials. Waves 1..3 park partials in LDS (tile reuse),
    // wave 0 sums + clamps + stores. C/D layout: col=lane&15, row=quad*4+reg.
    __syncthreads();
    if (w > 0) {
        float* red = (float*)smem + (w - 1) * (64 * 65);  // stride 65: no conflicts
#pragma unroll
        for (int ti = 0; ti < 4; ++ti)
#pragma unroll
            for (int tj = 0; tj < 4; ++tj)
#pragma unroll
                for (int r = 0; r < 4; ++r)
                    red[(ti * 16 + q * 4 + r) * 65 + tj * 16 + m] = acc[ti][tj][r];
    }
    __syncthreads();
    if (w == 0) {
        float* r0 = (float*)smem;
        float* r1 = r0 + 64 * 65;
        float* r2 = r1 + 64 * 65;
        float* ob = out + (size_t)b * (WIDTH * WIDTH);
#pragma unroll
        for (int ti = 0; ti < 4; ++ti)
#pragma unroll
            for (int tj = 0; tj < 4; ++tj)
#pragma unroll
                for (int r = 0; r < 4; ++r) {
                    int row = ti * 16 + q * 4 + r;
                    int col = tj * 16 + m;
                    int i = row - 2, j = col - 2;
                    if ((unsigned)i < WIDTH && (unsigned)j < WIDTH) {
                        float v = acc[ti][tj][r] + r0[row * 65 + col] +
                                  r1[row * 65 + col] + r2[row * 65 + col];
                        ob[i * WIDTH + j] = fminf(v, 1.0f);
                    }
                }
    }
}

extern "C" void kernel_launch(void* const* d_in, const int* in_sizes, int n_in,
                              void* d_out, int out_size, void* d_ws, size_t ws_size,
                              hipStream_t stream) {
    const float* x = (const float*)d_in[0];
    float* out = (float*)d_out;
    int B = in_sizes[0] / (LCURVES * 8);  // 256
    bezier_mfma_kernel<<<B, 256, 0, stream>>>(x, out);
}